// Round 14
// baseline (590.441 us; speedup 1.0000x reference)
//
#include <hip/hip_runtime.h>
#include <hip/hip_bf16.h>
#include <math.h>

#define NNODES   50000
#define INDIM    78
#define NHEADS   10
#define CDIM     78
#define HCDIM    780
#define NEDGES   400000
#define NBATCH   256
#define ETOT     (NEDGES + NNODES)   // 450000, with self-loops
#define NEG_SLOPE 0.2f

// GEMM2 MFMA tiling (BK=32 dbuf: 32 KB LDS -> 4 blocks/CU)
#define BM 128
#define BN 128
#define BK 32             // K-tile (26 iters over KPAD)
#define KPAD 832          // 26 * 32
#define NPAD 896          // 7 * 128
#define LDT 68            // transposed epilogue tile stride (ushorts)
#define NKT 26            // KPAD / BK
#define BUFO (2 * 128 * 32)   // ushorts per (As|Bs) buffer = 16 KB

// GEMM1 (fused xl|xr) tiling
#define KP1 96            // 78 padded to 3*32
#define NP1 1664          // 13 * 128  (780 xl | 780 xr | pad)

typedef __attribute__((ext_vector_type(8))) short bf16x8_t;
typedef __attribute__((ext_vector_type(4))) float f32x4_t;
typedef __attribute__((ext_vector_type(2))) float v2f;

__device__ __forceinline__ float bf2f(unsigned short u) {
    union { unsigned int i; float f; } v; v.i = ((unsigned int)u) << 16; return v.f;
}
__device__ __forceinline__ unsigned short f2bf(float f) {
    __hip_bfloat16 h = __float2bfloat16(f);
    return *reinterpret_cast<unsigned short*>(&h);
}
// packed pair of bf16 (even channel in low half) -> v2f
__device__ __forceinline__ v2f cvt2(unsigned int u) {
    union { unsigned int i; float f; } lo, hi;
    lo.i = u << 16;
    hi.i = u & 0xFFFF0000u;
    v2f r; r.x = lo.f; r.y = hi.f; return r;
}
__device__ __forceinline__ v2f vmax2(v2f a, v2f b) {
    v2f r; r.x = fmaxf(a.x, b.x); r.y = fmaxf(a.y, b.y); return r;
}
// sum over each 8-lane group via DPP (no LDS): xor1, xor2, half-mirror
__device__ __forceinline__ float dpp_red8(float x) {
    int y;
    y = __builtin_amdgcn_update_dpp(0, __float_as_int(x), 0xB1, 0xF, 0xF, true);
    x += __int_as_float(y);
    y = __builtin_amdgcn_update_dpp(0, __float_as_int(x), 0x4E, 0xF, 0xF, true);
    x += __int_as_float(y);
    y = __builtin_amdgcn_update_dpp(0, __float_as_int(x), 0x141, 0xF, 0xF, true);
    x += __int_as_float(y);
    return x;
}

// async global->LDS, 16 B per lane; LDS base wave-uniform (HW: base+lane*16)
__device__ __forceinline__ void async_ld16(const unsigned short* g, unsigned short* l) {
    __builtin_amdgcn_global_load_lds(
        (const __attribute__((address_space(1))) void*)g,
        (__attribute__((address_space(3))) void*)l, 16, 0, 0);
}

// ---------------------------------------------------------------------------
// zero-init (out for atomics + deg for CSR) in one launch
// ---------------------------------------------------------------------------
__global__ void zero_kernel(float* __restrict__ outp, int nf, int* __restrict__ deg, int ni) {
    int i = blockIdx.x * blockDim.x + threadIdx.x;
    if (i < nf) outp[i] = 0.f;
    if (i < ni) deg[i] = 0;
}

// ---------------------------------------------------------------------------
// CSR build
// ---------------------------------------------------------------------------
__global__ void count_kernel(const int* __restrict__ ei, int* __restrict__ deg) {
    int e = blockIdx.x * blockDim.x + threadIdx.x;
    if (e >= ETOT) return;
    int d = (e < NEDGES) ? ei[NEDGES + e] : (e - NEDGES);
    atomicAdd(&deg[d], 1);
}

__global__ void scan1_kernel(const int* __restrict__ deg, int* __restrict__ rowp,
                             int* __restrict__ bsum) {
    __shared__ int s[256];
    int t = threadIdx.x, b = blockIdx.x;
    int i = b * 256 + t;
    int v = (i < NNODES) ? deg[i] : 0;
    s[t] = v;
    __syncthreads();
    #pragma unroll
    for (int off = 1; off < 256; off <<= 1) {
        int y = (t >= off) ? s[t - off] : 0;
        __syncthreads();
        s[t] += y;
        __syncthreads();
    }
    int incl = s[t];
    if (i < NNODES) rowp[i] = incl - v;
    if (t == 255) bsum[b] = incl;
}

__global__ void scan2_kernel(int* __restrict__ bsum, int* __restrict__ rowp, int nblk,
                             const int* __restrict__ batch, int* __restrict__ bst) {
    __shared__ int s[256];
    int t = threadIdx.x;
    int v = 0;
    if (t < 256) { v = (t < nblk) ? bsum[t] : 0; s[t] = v; }
    __syncthreads();
    #pragma unroll
    for (int off = 1; off < 256; off <<= 1) {
        int y = (t < 256 && t >= off) ? s[t - off] : 0;
        __syncthreads();
        if (t < 256) s[t] += y;
        __syncthreads();
    }
    if (t < 256) {
        int incl = s[t];
        if (t < nblk) bsum[t] = incl - v;
        if (t == 255) rowp[NNODES] = incl;
    } else {
        int b = t - 256;
        int lo = 0, hi = NNODES;
        while (lo < hi) { int mid = (lo + hi) >> 1; if (batch[mid] < b) lo = mid + 1; else hi = mid; }
        bst[b] = lo;
        if (t == 511) bst[NBATCH] = NNODES;
    }
}

__global__ void scan3_kernel(int* __restrict__ rowp, const int* __restrict__ bsum,
                             int* __restrict__ curs, const int* __restrict__ deg,
                             float* __restrict__ dinv) {
    int i = blockIdx.x * 256 + threadIdx.x;
    if (i >= NNODES) return;
    int r = rowp[i] + bsum[i >> 8];
    rowp[i] = r;
    curs[i] = r;
    dinv[i] = rsqrtf((float)deg[i]);
}

__global__ void fill_kernel(const int* __restrict__ ei,
                            int* __restrict__ cursor, int* __restrict__ col) {
    int e = blockIdx.x * blockDim.x + threadIdx.x;
    if (e >= ETOT) return;
    int s, d;
    if (e < NEDGES) { s = ei[e]; d = ei[NEDGES + e]; }
    else            { s = d = e - NEDGES; }
    int pos = atomicAdd(&cursor[d], 1);
    col[pos] = s;
}

// ---------------------------------------------------------------------------
// Wc prep: Wc[n][k] = bf16([W_l|W_r]^T), zero-padded to [NP1][KP1=96]
// ---------------------------------------------------------------------------
__global__ void wprep_kernel(const float* __restrict__ Wl, const float* __restrict__ Wr,
                             unsigned short* __restrict__ Wc) {
    int idx = blockIdx.x * 256 + threadIdx.x;
    if (idx >= NP1 * KP1) return;
    int n = idx / KP1, k = idx - n * KP1;
    float v = 0.f;
    if (k < INDIM) {
        if (n < HCDIM)            v = Wl[(size_t)k * HCDIM + n];
        else if (n < 2 * HCDIM)   v = Wr[(size_t)k * HCDIM + (n - HCDIM)];
    }
    Wc[idx] = f2bf(v);
}

// ---------------------------------------------------------------------------
// GEMM1 fused MFMA v2: K padded to 96 (3 kc-chunks) — unchanged from R11.
// ---------------------------------------------------------------------------
__global__ __launch_bounds__(256) void gemm1_kernel(
        const float* __restrict__ x, const unsigned short* __restrict__ Wc,
        unsigned short* __restrict__ xl, unsigned short* __restrict__ xr, int M) {
    __shared__ unsigned short As[3 * 4096];
    __shared__ unsigned short Bs[3 * 4096];
    int t = threadIdx.x;
    int lane = t & 63, w = t >> 6;
    int bm = blockIdx.x * 128;

    for (int idx = t; idx < 128 * KP1; idx += 256) {
        int row = idx / KP1, k = idx - row * KP1;
        int kc = k >> 5, ch = (k >> 3) & 3, e = k & 7;
        int gr = bm + row;
        float v = (gr < M && k < INDIM) ? x[(size_t)gr * INDIM + k] : 0.f;
        As[kc * 4096 + row * 32 + (((ch + (row >> 1)) & 3) * 8) + e] = f2bf(v);
    }

    int lrow = lane >> 2;
    int gch = ((lane & 3) - (lane >> 3)) & 3;
    int m16 = lane & 15, q = lane >> 4;
    int wr = (w >> 1) * 64, wcc = (w & 1) * 64;

    for (int nb = 0; nb < 13; nb++) {
        __syncthreads();
        #pragma unroll
        for (int kc = 0; kc < 3; kc++) {
            const unsigned short* gb = Wc + ((size_t)(nb * 128 + 32 * w + lrow)) * KP1
                                          + kc * 32 + gch * 8;
            unsigned short* lb = Bs + kc * 4096 + (32 * w) * 32;
            async_ld16(gb, lb);
            async_ld16(gb + 16 * KP1, lb + 16 * 32);
        }
        __syncthreads();

        f32x4_t acc[4][4];
        #pragma unroll
        for (int i = 0; i < 4; i++)
            #pragma unroll
            for (int j = 0; j < 4; j++)
                acc[i][j] = (f32x4_t)(0.f);

        #pragma unroll
        for (int kc = 0; kc < 3; kc++) {
            bf16x8_t af[4], bf[4];
            #pragma unroll
            for (int i = 0; i < 4; i++) {
                int row = wr + i * 16 + m16;
                af[i] = *(const bf16x8_t*)&As[kc * 4096 + row * 32 + (((q + (row >> 1)) & 3) * 8)];
            }
            #pragma unroll
            for (int j = 0; j < 4; j++) {
                int row = wcc + j * 16 + m16;
                bf[j] = *(const bf16x8_t*)&Bs[kc * 4096 + row * 32 + (((q + (row >> 1)) & 3) * 8)];
            }
            #pragma unroll
            for (int i = 0; i < 4; i++)
                #pragma unroll
                for (int j = 0; j < 4; j++)
                    acc[i][j] = __builtin_amdgcn_mfma_f32_16x16x32_bf16(af[i], bf[j], acc[i][j], 0, 0, 0);
        }

        #pragma unroll
        for (int j = 0; j < 4; j++) {
            int ng = nb * 128 + wcc + j * 16 + m16;
            if (ng >= 2 * HCDIM) continue;
            unsigned short* dst = (ng < HCDIM) ? (xl + ng) : (xr + (ng - HCDIM));
            #pragma unroll
            for (int i = 0; i < 4; i++) {
                #pragma unroll
                for (int rr = 0; rr < 4; rr++) {
                    int row = bm + wr + i * 16 + q * 4 + rr;
                    if (row < M) dst[(size_t)row * HCDIM] = f2bf(acc[i][j][rr]);
                }
            }
        }
    }
}

// ---------------------------------------------------------------------------
// GATv2 aggregation v6 (stable: 8-lane groups, 5 waves per 4 nodes).
// ---------------------------------------------------------------------------
__device__ __forceinline__ void gat_body8(
        const char* __restrict__ xlb, unsigned bo, bool lo7, bool live,
        v2f r0, v2f r1, v2f r2, v2f r3, v2f r4,
        v2f a0, v2f a1, v2f a2, v2f a3, v2f a4,
        float& l, v2f& c0, v2f& c1, v2f& c2, v2f& c3, v2f& c4) {
    const unsigned int* p = (const unsigned int*)(xlb + bo);
    unsigned int u0 = p[0];
    unsigned int u1 = p[8];
    unsigned int u2 = p[16];
    unsigned int u3 = p[24];
    unsigned int u4 = lo7 ? p[32] : 0u;
    v2f v0 = cvt2(u0), v1 = cvt2(u1), v2v = cvt2(u2), v3 = cvt2(u3), v4 = cvt2(u4);
    v2f t0 = v0 + r0, t1 = v1 + r1, t2 = v2v + r2, t3 = v3 + r3, t4 = v4 + r4;
    v2f m0 = vmax2(t0, t0 * 0.2f);
    v2f m1 = vmax2(t1, t1 * 0.2f);
    v2f m2 = vmax2(t2, t2 * 0.2f);
    v2f m3 = vmax2(t3, t3 * 0.2f);
    v2f m4 = vmax2(t4, t4 * 0.2f);
    v2f s2 = m0 * a0;
    s2 += m1 * a1;
    s2 += m2 * a2;
    s2 += m3 * a3;
    s2 += m4 * a4;
    float part = dpp_red8(s2.x + s2.y);
    float pp = __builtin_amdgcn_exp2f(part);
    pp = live ? pp : 0.f;
    l += pp;
    c0 += pp * v0; c1 += pp * v1; c2 += pp * v2v; c3 += pp * v3; c4 += pp * v4;
}

__global__ __launch_bounds__(256) void gat_kernel(
        const unsigned short* __restrict__ xl, const unsigned short* xr,
        const int* __restrict__ row_ptr, const int* __restrict__ col,
        const float* __restrict__ att, const float* __restrict__ bias1,
        unsigned short* h_out) {
    int wid = blockIdx.x * 4 + (threadIdx.x >> 6);
    int quad = wid / 5;
    int wavein = wid - 5 * quad;
    int lane = threadIdx.x & 63;
    int g = lane >> 3, gl = lane & 7;
    int tau = 8 * wavein + g;            // 0..39 task within quad
    int nl = tau / 10;                   // 0..3
    int head = tau - 10 * nl;            // 0..9
    int node = 4 * quad + nl;
    bool lo7 = gl < 7;

    const float L2E = 1.4426950408889634f;
    const float2* ap = (const float2*)(att + head * CDIM);
    float2 A0 = ap[gl], A1 = ap[gl + 8], A2 = ap[gl + 16], A3 = ap[gl + 24];
    float2 A4 = lo7 ? ap[gl + 32] : make_float2(0.f, 0.f);
    v2f a0, a1, a2, a3, a4;
    a0.x = A0.x * L2E; a0.y = A0.y * L2E;
    a1.x = A1.x * L2E; a1.y = A1.y * L2E;
    a2.x = A2.x * L2E; a2.y = A2.y * L2E;
    a3.x = A3.x * L2E; a3.y = A3.y * L2E;
    a4.x = A4.x * L2E; a4.y = A4.y * L2E;

    unsigned doffb = (unsigned)(head * (CDIM * 2) + gl * 4);    // byte off in row
    const char* xlb = (const char*)xl;
    const unsigned int* rp = (const unsigned int*)((const char*)xr
                              + (unsigned)node * (unsigned)(HCDIM * 2) + doffb);
    v2f r0 = cvt2(rp[0]);
    v2f r1 = cvt2(rp[8]);
    v2f r2 = cvt2(rp[16]);
    v2f r3 = cvt2(rp[24]);
    v2f r4 = lo7 ? cvt2(rp[32]) : (v2f)(0.f);

    int e0 = row_ptr[node], e1 = row_ptr[node + 1];
    int deg = e1 - e0;                                  // >= 1 (self-loop)
    int dF = __builtin_amdgcn_readlane(deg, 0);
    int dL = __builtin_amdgcn_readlane(deg, 63);
    int iters = dF > dL ? dF : dL;

    float l = 0.f;
    v2f c0 = (v2f)(0.f), c1 = (v2f)(0.f), c2 = (v2f)(0.f), c3 = (v2f)(0.f), c4 = (v2f)(0.f);

    const char* colb = (const char*)col;
    unsigned cbase = (unsigned)e0 * 4u;
    unsigned cmax = (unsigned)(deg - 1) * 4u;
    for (int i = 0; i < iters; i += 2) {
        unsigned io = (unsigned)i * 4u;
        unsigned q1 = io < cmax ? io : cmax;
        unsigned io2 = io + 4u;
        unsigned q2 = io2 < cmax ? io2 : cmax;
        int j1 = *(const int*)(colb + (cbase + q1));    // clamped: in-bounds
        int j2 = *(const int*)(colb + (cbase + q2));
        bool lv1 = i < deg;
        bool lv2 = (i + 1) < deg;
        gat_body8(xlb, (unsigned)j1 * (unsigned)(HCDIM * 2) + doffb, lo7, lv1,
                  r0, r1, r2, r3, r4, a0, a1, a2, a3, a4, l, c0, c1, c2, c3, c4);
        gat_body8(xlb, (unsigned)j2 * (unsigned)(HCDIM * 2) + doffb, lo7, lv2,
                  r0, r1, r2, r3, r4, a0, a1, a2, a3, a4, l, c0, c1, c2, c3, c4);
    }

    float inv = 1.f / l;                 // l > 0 (self-loop)
    const float2* bp = (const float2*)(bias1 + head * CDIM);
    unsigned int* op = (unsigned int*)((char*)h_out
                        + (unsigned)node * (unsigned)(HCDIM * 2) + doffb);
    #pragma unroll
    for (int k = 0; k < 5; k++) {
        if (k == 4 && !lo7) break;
        v2f c = (k == 0) ? c0 : (k == 1) ? c1 : (k == 2) ? c2 : (k == 3) ? c3 : c4;
        float2 bb = bp[gl + 8 * k];
        float x0 = c.x * inv + bb.x;
        float x1 = c.y * inv + bb.y;
        x0 = x0 > 0.f ? x0 : (__expf(x0) - 1.f);   // ELU
        x1 = x1 > 0.f ? x1 : (__expf(x1) - 1.f);
        op[8 * k] = (unsigned int)f2bf(x0) | ((unsigned int)f2bf(x1) << 16);
    }
}

// ---------------------------------------------------------------------------
// GCN aggregation v4: 2-deep software pipeline (unchanged from R8, -15 µs).
// ---------------------------------------------------------------------------
__device__ __forceinline__ void gcn_consume(
        float s, bf16x8_t u, ushort4 v4, ushort4 w4,
        float* __restrict__ accA, float* __restrict__ accB, float* __restrict__ accC) {
    #pragma unroll
    for (int k = 0; k < 8; k++) accA[k] = fmaf(s, bf2f((unsigned short)u[k]), accA[k]);
    accB[0] = fmaf(s, bf2f(v4.x), accB[0]);
    accB[1] = fmaf(s, bf2f(v4.y), accB[1]);
    accB[2] = fmaf(s, bf2f(v4.z), accB[2]);
    accB[3] = fmaf(s, bf2f(v4.w), accB[3]);
    accC[0] = fmaf(s, bf2f(w4.x), accC[0]);
    accC[1] = fmaf(s, bf2f(w4.y), accC[1]);
    accC[2] = fmaf(s, bf2f(w4.z), accC[2]);
    accC[3] = fmaf(s, bf2f(w4.w), accC[3]);
}

__global__ __launch_bounds__(256) void gcn_agg_kernel(
        const unsigned short* __restrict__ h, const int* __restrict__ row_ptr,
        const int* __restrict__ col, const float* __restrict__ dinv,
        unsigned short* __restrict__ agg) {
    int node = blockIdx.x * 4 + (threadIdx.x >> 6);
    if (node >= NNODES) return;
    int ln = threadIdx.x & 63;
    bool hasC = ln < 3;
    float accA[8] = {}, accB[4] = {}, accC[4] = {};
    int e0 = row_ptr[node], e1 = row_ptr[node + 1];   // deg >= 1 (self-loop)

    // state 0 <- edge e0
    int j0 = __builtin_amdgcn_readfirstlane(col[e0]);
    const unsigned short* hr0 = h + (size_t)j0 * HCDIM;
    bf16x8_t u0 = *(const bf16x8_t*)(hr0 + 8 * ln);
    ushort4 v0 = *(const ushort4*)(hr0 + 512 + 4 * ln);
    ushort4 w0 = hasC ? *(const ushort4*)(hr0 + 768 + 4 * ln) : make_ushort4(0, 0, 0, 0);
    float s0 = dinv[j0];

    int e = e0;
    for (;;) {
        bool m1 = (e + 1 < e1);
        bf16x8_t u1; ushort4 v1, w1; float s1;
        if (m1) {   // prefetch edge e+1 into state 1 before consuming state 0
            int j1 = __builtin_amdgcn_readfirstlane(col[e + 1]);
            const unsigned short* hr1 = h + (size_t)j1 * HCDIM;
            u1 = *(const bf16x8_t*)(hr1 + 8 * ln);
            v1 = *(const ushort4*)(hr1 + 512 + 4 * ln);
            w1 = hasC ? *(const ushort4*)(hr1 + 768 + 4 * ln) : make_ushort4(0, 0, 0, 0);
            s1 = dinv[j1];
        }
        gcn_consume(s0, u0, v0, w0, accA, accB, accC);
        if (!m1) break;
        e++;
        bool m2 = (e + 1 < e1);
        if (m2) {   // prefetch edge e+1 into state 0 before consuming state 1
            int j2 = __builtin_amdgcn_readfirstlane(col[e + 1]);
            const unsigned short* hr2 = h + (size_t)j2 * HCDIM;
            u0 = *(const bf16x8_t*)(hr2 + 8 * ln);
            v0 = *(const ushort4*)(hr2 + 512 + 4 * ln);
            w0 = hasC ? *(const ushort4*)(hr2 + 768 + 4 * ln) : make_ushort4(0, 0, 0, 0);
            s0 = dinv[j2];
        }
        gcn_consume(s1, u1, v1, w1, accA, accB, accC);
        if (!m2) break;
        e++;
    }

    float di = dinv[node];
    unsigned short* ar = agg + (size_t)node * HCDIM;
    ushort4 o1, o2, ob;
    o1.x = f2bf(accA[0] * di); o1.y = f2bf(accA[1] * di);
    o1.z = f2bf(accA[2] * di); o1.w = f2bf(accA[3] * di);
    o2.x = f2bf(accA[4] * di); o2.y = f2bf(accA[5] * di);
    o2.z = f2bf(accA[6] * di); o2.w = f2bf(accA[7] * di);
    ob.x = f2bf(accB[0] * di); ob.y = f2bf(accB[1] * di);
    ob.z = f2bf(accB[2] * di); ob.w = f2bf(accB[3] * di);
    *(ushort4*)(ar + 8 * ln) = o1;
    *(ushort4*)(ar + 8 * ln + 4) = o2;
    *(ushort4*)(ar + 512 + 4 * ln) = ob;
    if (hasC) {
        ushort4 oc;
        oc.x = f2bf(accC[0] * di); oc.y = f2bf(accC[1] * di);
        oc.z = f2bf(accC[2] * di); oc.w = f2bf(accC[3] * di);
        *(ushort4*)(ar + 768 + 4 * ln) = oc;
    }
}

// ---------------------------------------------------------------------------
// BT prep: BT[n][k] = bf16(W_gcn[k][n]), zero-padded to [NPAD][KPAD]
// ---------------------------------------------------------------------------
__global__ void btprep_kernel(const float* __restrict__ W, unsigned short* __restrict__ BT) {
    int idx = blockIdx.x * 256 + threadIdx.x;
    if (idx >= NPAD * KPAD) return;
    int n = idx / KPAD, k = idx - n * KPAD;
    float v = (n < HCDIM && k < HCDIM) ? W[(size_t)k * HCDIM + n] : 0.f;
    BT[idx] = f2bf(v);
}

// ---------------------------------------------------------------------------
// GEMM2 MFMA fused v10: BK=32 dbuf (4 blocks/CU) + degree-2 rotation
// swizzle. R12 measured 9.1M bank conflicts: with 64-B rows the bank
// period (2 rows) vs rotation period (4) left rows r,r+4,r+8,r+12 on the
// SAME 4-bank group (4-way, 1.58x). Fix: fold row>>2 into the rotation —
// read slot c=(q+row+(row>>2))&3, write src gch=(c4-lrow4-(lrow4>>2))&3.
// Invariant under row+16/+32 (20,40 ≡ 0 mod 4) so one gch serves all ib/w;
// slot->chunk bijection preserved (read returns global chunk q). 2-way = free.
// ---------------------------------------------------------------------------
__global__ __launch_bounds__(256) void gemm2_pool_kernel(
        const unsigned short* __restrict__ A, const unsigned short* __restrict__ BT,
        const float* __restrict__ bias, const int* __restrict__ batch,
        float* __restrict__ out, int M) {
    int f = blockIdx.x;
    int xcd = f & 7, inner = f >> 3;
    int bq = inner / 7, colt = inner - 7 * bq;
    int band = 8 * bq + xcd;
    if (band >= (M + BM - 1) / BM) return;   // block-uniform
    int bm = band * BM, bn = colt * BN;

    __shared__ unsigned short smem[2 * BUFO];       // 32 KB: {buf}{As|Bs}[128][32]
    __shared__ int bsh[BM];

    int t = threadIdx.x;
    int lane = t & 63, w = t >> 6;

    if (t < BM) {
        int row = bm + t;
        bsh[t] = (row < M) ? batch[row] : -1;
    }

    int m16 = lane & 15, q = lane >> 4;
    int wr = (w >> 1) * 64, wc = (w & 1) * 64;

    // live 16-col groups for this wave (wave-uniform): 4 for full tiles,
    // 1 for tail tile wc=0 (cols 768..783 -> 12 real), 0 for tail wc=64.
    int remc = HCDIM - bn - wc;
    int nj = (remc >= 64) ? 4 : (remc > 0 ? ((remc + 15) >> 4) : 0);

    int lrow4 = lane >> 2;              // 16 rows per load instruction
    int c4 = lane & 3;
    int gch = (c4 - lrow4 - (lrow4 >> 2)) & 3;   // degree-2 pre-swizzled chunk
    const unsigned short* gA = A  + (size_t)(bm + 32 * w + lrow4) * HCDIM + gch * 8;
    const unsigned short* gB = BT + (size_t)(bn + 32 * w + lrow4) * KPAD  + gch * 8;
    unsigned short* lA = smem + (32 * w) * 32;              // + buf*BUFO
    unsigned short* lB = smem + 128 * 32 + (32 * w) * 32;   // + buf*BUFO

    f32x4_t acc[4][4];
    #pragma unroll
    for (int i = 0; i < 4; i++)
        #pragma unroll
        for (int j = 0; j < 4; j++)
            acc[i][j] = (f32x4_t)(0.f);

    // prologue: stage tile 0 into buf 0 (4 loads/thread); counted wait in loop
    #pragma unroll
    for (int ib = 0; ib < 2; ib++) {
        async_ld16(gA + (size_t)(16 * ib) * HCDIM, lA + (16 * ib) * 32);
        async_ld16(gB + (size_t)(16 * ib) * KPAD,  lB + (16 * ib) * 32);
    }

    for (int tt = 0; tt < NKT; tt++) {
        int cur = tt & 1;
        // issue next tile's loads; they STAY IN FLIGHT across the barrier
        if (tt + 1 < NKT) {
            int k0 = (tt + 1) * BK;
            unsigned short* dA = lA + (cur ? 0 : BUFO);
            unsigned short* dB = lB + (cur ? 0 : BUFO);
            #pragma unroll
            for (int ib = 0; ib < 2; ib++) {
                async_ld16(gA + (size_t)(16 * ib) * HCDIM + k0, dA + (16 * ib) * 32);
                async_ld16(gB + (size_t)(16 * ib) * KPAD  + k0, dB + (16 * ib) * 32);
            }
            asm volatile("s_waitcnt vmcnt(4)" ::: "memory");   // tile tt landed
        } else {
            asm volatile("s_waitcnt vmcnt(0)" ::: "memory");   // last tile
        }
        __builtin_amdgcn_s_barrier();   // publish all waves' tile-tt LDS writes

        const unsigned short* As = smem + (cur ? BUFO : 0);
        const unsigned short* Bs = As + 128 * 32;

        if (nj > 0) {
            bf16x8_t af[4], bf[4];
            #pragma unroll
            for (int i = 0; i < 4; i++) {
                int row = wr + i * 16 + m16;
                af[i] = *(const bf16x8_t*)&As[row * 32 + ((q + row + (row >> 2)) & 3) * 8];
            }
            #pragma unroll
            for (int j = 0; j < 4; j++) {
                if (j >= nj) break;
                int row = wc + j * 16 + m16;
                bf[j] = *(const bf16x8_t*)&Bs[row * 32 + ((q + row + (row >> 2)) & 3) * 8];
            }
            #pragma unroll
            for (int j = 0; j < 4; j++) {
                if (j >= nj) break;
                #pragma unroll
                for (int i = 0; i < 4; i++)
                    acc[i][j] = __builtin_amdgcn_mfma_f32_16x16x32_bf16(af[i], bf[j], acc[i][j], 0, 0, 0);
            }
        }

        // all waves done reading buf[cur] before iter tt+1 overwrites it
        __builtin_amdgcn_s_barrier();
    }

    float bvj[4];
    #pragma unroll
    for (int j = 0; j < 4; j++) {
        int gcc = bn + wc + j * 16 + m16;
        bvj[j] = (gcc < HCDIM) ? bias[gcc] : 0.f;
    }

    #pragma unroll
    for (int p = 0; p < 2; p++) {
        __syncthreads();
        if ((w >> 1) == p) {
            #pragma unroll
            for (int i = 0; i < 4; i++) {
                #pragma unroll
                for (int j = 0; j < 4; j++) {
                    int colc = wc + j * 16 + m16;
                    ushort4 o;
                    float v0 = acc[i][j][0] + bvj[j];
                    float v1 = acc[i][j][1] + bvj[j];
                    float v2 = acc[i][j][2] + bvj[j];
                    float v3 = acc[i][j][3] + bvj[j];
                    o.x = f2bf(v0 > 0.f ? v0 : 0.f);
                    o.y = f2bf(v1 > 0.f ? v1 : 0.f);
                    o.z = f2bf(v2 > 0.f ? v2 : 0.f);
                    o.w = f2bf(v3 > 0.f ? v3 : 0.f);
                    *(ushort4*)&smem[colc * LDT + i * 16 + q * 4] = o;
                }
            }
        }
        __syncthreads();
        int colp = t & 127;
        int rb = (t >> 7) * 32;
        int gc = bn + colp;
        if (gc < HCDIM) {
            int cur = -1; float mx = 0.f, sm = 0.f;
            bool done = false;
            for (int rr = rb; rr < rb + 32 && !done; rr += 4) {
                ushort4 u = *(const ushort4*)&smem[colp * LDT + rr];
                unsigned short us[4] = {u.x, u.y, u.z, u.w};
                #pragma unroll
                for (int s2 = 0; s2 < 4; s2++) {
                    int b = bsh[64 * p + rr + s2];
                    if (b < 0) { done = true; break; }
                    float v = bf2f(us[s2]);
                    if (b != cur) {
                        if (cur >= 0) {
                            atomicMax((int*)(out + (size_t)cur * (2 * HCDIM) + gc), __float_as_int(mx));
                            atomicAdd(out + (size_t)cur * (2 * HCDIM) + HCDIM + gc, sm);
                        }
                        cur = b; mx = v; sm = v;
                    } else { mx = fmaxf(mx, v); sm += v; }
                }
            }
            if (cur >= 0) {
                atomicMax((int*)(out + (size_t)cur * (2 * HCDIM) + gc), __float_as_int(mx));
                atomicAdd(out + (size_t)cur * (2 * HCDIM) + HCDIM + gc, sm);
            }
        }
    }
}

// divide the mean slots by counts
__global__ void finalize_kernel(float* __restrict__ out, const int* __restrict__ bst) {
    int i = blockIdx.x * blockDim.x + threadIdx.x;
    if (i >= NBATCH * HCDIM) return;
    int b = i / HCDIM, c = i - b * HCDIM;
    int cnt = bst[b + 1] - bst[b];
    out[(size_t)b * (2 * HCDIM) + HCDIM + c] /= (float)(cnt > 0 ? cnt : 1);
}

// ---------------------------------------------------------------------------
extern "C" void kernel_launch(void* const* d_in, const int* in_sizes, int n_in,
                              void* d_out, int out_size, void* d_ws, size_t ws_size,
                              hipStream_t stream) {
    const float* x       = (const float*)d_in[0];
    const int*   ei      = (const int*)d_in[1];
    const int*   batch   = (const int*)d_in[2];
    const float* W_l     = (const float*)d_in[3];
    const float* W_r     = (const float*)d_in[4];
    const float* att     = (const float*)d_in[5];
    const float* bias1   = (const float*)d_in[6];
    const float* W_gcn   = (const float*)d_in[7];
    const float* bias_gcn= (const float*)d_in[8];
    float* out = (float*)d_out;

    char* w = (char*)d_ws;
    const size_t BIGH = (size_t)NNODES * HCDIM * sizeof(unsigned short);  // 78,000,000
    unsigned short* xl  = (unsigned short*)(w);          // later reused as agg
    unsigned short* xr  = (unsigned short*)(w + BIGH);   // becomes h; later BT
    unsigned short* agg = xl;
    unsigned short* BT  = xr;                            // h dead after gcn_agg
    char* sm = w + 2 * BIGH;
    int*   rowp = (int*)(sm);                    sm += 50048 * 4;
    int*   col  = (int*)(sm);                    sm += 450048 * 4;
    float* dinv = (float*)(sm);                  sm += 50048 * 4;
    int*   bst  = (int*)(sm);                    sm += 512 * 4;
    int*   bsum = (int*)(sm);                    sm += 256 * 4;
    char* S = sm;                                sm += 426240;
    int*   deg  = (int*)(S);
    int*   curs = (int*)(S + 200192);
    unsigned short* Wc = (unsigned short*)(S);   // NP1*KP1*2 = 319,488 B < 426,240
    size_t needed = (size_t)(sm - (char*)d_ws);
    if (ws_size < needed) return;   // fail soft instead of OOB fault

    // --- zero-init (out for atomics + deg) ---
    zero_kernel<<<(NBATCH * 2 * HCDIM + 255) / 256, 256, 0, stream>>>(
        out, NBATCH * 2 * HCDIM, deg, NNODES);

    // --- CSR build ---
    {
        int eblocks = (ETOT + 255) / 256;
        int nblocks = (NNODES + 255) / 256;     // 196
        count_kernel<<<eblocks, 256, 0, stream>>>(ei, deg);
        scan1_kernel<<<nblocks, 256, 0, stream>>>(deg, rowp, bsum);
        scan2_kernel<<<1, 512, 0, stream>>>(bsum, rowp, nblocks, batch, bst);
        scan3_kernel<<<nblocks, 256, 0, stream>>>(rowp, bsum, curs, deg, dinv);
        fill_kernel<<<eblocks, 256, 0, stream>>>(ei, curs, col);
    }

    // --- Wc = [W_l|W_r]^T bf16 padded to K=96 (overwrites deg/curs) ---
    wprep_kernel<<<(NP1 * KP1 + 255) / 256, 256, 0, stream>>>(W_l, W_r, Wc);

    // --- fused GEMM1 (MFMA, K=96): xl|xr = x @ [W_l|W_r] ---
    gemm1_kernel<<<(NNODES + 127) / 128, 256, 0, stream>>>(x, Wc, xl, xr, NNODES);

    // --- GATv2 + ELU (writes h over xr); v6: 5 waves per 4 nodes ---
    {
        int waves = (NNODES / 4) * 5;          // 62500
        int blocks = waves / 4;                // 15625 (exact)
        gat_kernel<<<blocks, 256, 0, stream>>>(xl, xr, rowp, col, att, bias1, xr);
    }

    // --- GCN aggregate (h -> agg, overwrites xl space; 2-deep pipelined) ---
    gcn_agg_kernel<<<(NNODES + 3) / 4, 256, 0, stream>>>(xr, rowp, col, dinv, agg);

    // --- W_gcn^T -> bf16 padded (into xr region; h is dead) ---
    btprep_kernel<<<(NPAD * KPAD + 255) / 256, 256, 0, stream>>>(W_gcn, BT);

    // --- GEMM2 (MFMA, BK=32 dbuf, 4 blocks/CU, conflict-free swizzle) ---
    {
        int nb = (NNODES + BM - 1) / BM;       // 391
        int gx = 8 * ((nb + 7) / 8) * 7;       // 2744
        gemm2_pool_kernel<<<gx, 256, 0, stream>>>(agg, BT, bias_gcn, batch, out, NNODES);
    }

    // --- finalize means ---
    finalize_kernel<<<(NBATCH * HCDIM + 255) / 256, 256, 0, stream>>>(out, bst);
}

// Round 15
// 579.772 us; speedup vs baseline: 1.0184x; 1.0184x over previous
//
#include <hip/hip_runtime.h>
#include <hip/hip_bf16.h>
#include <math.h>

#define NNODES   50000
#define INDIM    78
#define NHEADS   10
#define CDIM     78
#define HCDIM    780
#define NEDGES   400000
#define NBATCH   256
#define ETOT     (NEDGES + NNODES)   // 450000, with self-loops
#define NEG_SLOPE 0.2f

// GEMM2 MFMA tiling (BK=32 dbuf: 32 KB LDS -> 4 blocks/CU)
#define BM 128
#define BN 128
#define BK 32             // K-tile (25 iters over KPAD)
#define KPAD 800          // 25 * 32 (was 832 — dead K-tile removed)
#define NPAD 896          // 7 * 128
#define LDT 68            // transposed epilogue tile stride (ushorts)
#define NKT 25            // KPAD / BK
#define BUFO (2 * 128 * 32)   // ushorts per (As|Bs) buffer = 16 KB

// GEMM1 (fused xl|xr) tiling
#define KP1 96            // 78 padded to 3*32
#define NP1 1664          // 13 * 128  (780 xl | 780 xr | pad)

typedef __attribute__((ext_vector_type(8))) short bf16x8_t;
typedef __attribute__((ext_vector_type(4))) float f32x4_t;
typedef __attribute__((ext_vector_type(2))) float v2f;

__device__ __forceinline__ float bf2f(unsigned short u) {
    union { unsigned int i; float f; } v; v.i = ((unsigned int)u) << 16; return v.f;
}
__device__ __forceinline__ unsigned short f2bf(float f) {
    __hip_bfloat16 h = __float2bfloat16(f);
    return *reinterpret_cast<unsigned short*>(&h);
}
// packed pair of bf16 (even channel in low half) -> v2f
__device__ __forceinline__ v2f cvt2(unsigned int u) {
    union { unsigned int i; float f; } lo, hi;
    lo.i = u << 16;
    hi.i = u & 0xFFFF0000u;
    v2f r; r.x = lo.f; r.y = hi.f; return r;
}
__device__ __forceinline__ v2f vmax2(v2f a, v2f b) {
    v2f r; r.x = fmaxf(a.x, b.x); r.y = fmaxf(a.y, b.y); return r;
}
// sum over each 8-lane group via DPP (no LDS): xor1, xor2, half-mirror
__device__ __forceinline__ float dpp_red8(float x) {
    int y;
    y = __builtin_amdgcn_update_dpp(0, __float_as_int(x), 0xB1, 0xF, 0xF, true);
    x += __int_as_float(y);
    y = __builtin_amdgcn_update_dpp(0, __float_as_int(x), 0x4E, 0xF, 0xF, true);
    x += __int_as_float(y);
    y = __builtin_amdgcn_update_dpp(0, __float_as_int(x), 0x141, 0xF, 0xF, true);
    x += __int_as_float(y);
    return x;
}

// async global->LDS, 16 B per lane; LDS base wave-uniform (HW: base+lane*16)
__device__ __forceinline__ void async_ld16(const unsigned short* g, unsigned short* l) {
    __builtin_amdgcn_global_load_lds(
        (const __attribute__((address_space(1))) void*)g,
        (__attribute__((address_space(3))) void*)l, 16, 0, 0);
}

// ---------------------------------------------------------------------------
// zero-init (out for atomics + deg for CSR) in one launch
// ---------------------------------------------------------------------------
__global__ void zero_kernel(float* __restrict__ outp, int nf, int* __restrict__ deg, int ni) {
    int i = blockIdx.x * blockDim.x + threadIdx.x;
    if (i < nf) outp[i] = 0.f;
    if (i < ni) deg[i] = 0;
}

// ---------------------------------------------------------------------------
// CSR build
// ---------------------------------------------------------------------------
__global__ void count_kernel(const int* __restrict__ ei, int* __restrict__ deg) {
    int e = blockIdx.x * blockDim.x + threadIdx.x;
    if (e >= ETOT) return;
    int d = (e < NEDGES) ? ei[NEDGES + e] : (e - NEDGES);
    atomicAdd(&deg[d], 1);
}

__global__ void scan1_kernel(const int* __restrict__ deg, int* __restrict__ rowp,
                             int* __restrict__ bsum) {
    __shared__ int s[256];
    int t = threadIdx.x, b = blockIdx.x;
    int i = b * 256 + t;
    int v = (i < NNODES) ? deg[i] : 0;
    s[t] = v;
    __syncthreads();
    #pragma unroll
    for (int off = 1; off < 256; off <<= 1) {
        int y = (t >= off) ? s[t - off] : 0;
        __syncthreads();
        s[t] += y;
        __syncthreads();
    }
    int incl = s[t];
    if (i < NNODES) rowp[i] = incl - v;
    if (t == 255) bsum[b] = incl;
}

__global__ void scan2_kernel(int* __restrict__ bsum, int* __restrict__ rowp, int nblk,
                             const int* __restrict__ batch, int* __restrict__ bst) {
    __shared__ int s[256];
    int t = threadIdx.x;
    int v = 0;
    if (t < 256) { v = (t < nblk) ? bsum[t] : 0; s[t] = v; }
    __syncthreads();
    #pragma unroll
    for (int off = 1; off < 256; off <<= 1) {
        int y = (t < 256 && t >= off) ? s[t - off] : 0;
        __syncthreads();
        if (t < 256) s[t] += y;
        __syncthreads();
    }
    if (t < 256) {
        int incl = s[t];
        if (t < nblk) bsum[t] = incl - v;
        if (t == 255) rowp[NNODES] = incl;
    } else {
        int b = t - 256;
        int lo = 0, hi = NNODES;
        while (lo < hi) { int mid = (lo + hi) >> 1; if (batch[mid] < b) lo = mid + 1; else hi = mid; }
        bst[b] = lo;
        if (t == 511) bst[NBATCH] = NNODES;
    }
}

__global__ void scan3_kernel(int* __restrict__ rowp, const int* __restrict__ bsum,
                             int* __restrict__ curs, const int* __restrict__ deg,
                             float* __restrict__ dinv) {
    int i = blockIdx.x * 256 + threadIdx.x;
    if (i >= NNODES) return;
    int r = rowp[i] + bsum[i >> 8];
    rowp[i] = r;
    curs[i] = r;
    dinv[i] = rsqrtf((float)deg[i]);
}

__global__ void fill_kernel(const int* __restrict__ ei,
                            int* __restrict__ cursor, int* __restrict__ col) {
    int e = blockIdx.x * blockDim.x + threadIdx.x;
    if (e >= ETOT) return;
    int s, d;
    if (e < NEDGES) { s = ei[e]; d = ei[NEDGES + e]; }
    else            { s = d = e - NEDGES; }
    int pos = atomicAdd(&cursor[d], 1);
    col[pos] = s;
}

// ---------------------------------------------------------------------------
// Wc prep: Wc[n][k] = bf16([W_l|W_r]^T), zero-padded to [NP1][KP1=96]
// ---------------------------------------------------------------------------
__global__ void wprep_kernel(const float* __restrict__ Wl, const float* __restrict__ Wr,
                             unsigned short* __restrict__ Wc) {
    int idx = blockIdx.x * 256 + threadIdx.x;
    if (idx >= NP1 * KP1) return;
    int n = idx / KP1, k = idx - n * KP1;
    float v = 0.f;
    if (k < INDIM) {
        if (n < HCDIM)            v = Wl[(size_t)k * HCDIM + n];
        else if (n < 2 * HCDIM)   v = Wr[(size_t)k * HCDIM + (n - HCDIM)];
    }
    Wc[idx] = f2bf(v);
}

// ---------------------------------------------------------------------------
// GEMM1 fused MFMA v2: K padded to 96 (3 kc-chunks) — unchanged from R11.
// ---------------------------------------------------------------------------
__global__ __launch_bounds__(256) void gemm1_kernel(
        const float* __restrict__ x, const unsigned short* __restrict__ Wc,
        unsigned short* __restrict__ xl, unsigned short* __restrict__ xr, int M) {
    __shared__ unsigned short As[3 * 4096];
    __shared__ unsigned short Bs[3 * 4096];
    int t = threadIdx.x;
    int lane = t & 63, w = t >> 6;
    int bm = blockIdx.x * 128;

    for (int idx = t; idx < 128 * KP1; idx += 256) {
        int row = idx / KP1, k = idx - row * KP1;
        int kc = k >> 5, ch = (k >> 3) & 3, e = k & 7;
        int gr = bm + row;
        float v = (gr < M && k < INDIM) ? x[(size_t)gr * INDIM + k] : 0.f;
        As[kc * 4096 + row * 32 + (((ch + (row >> 1)) & 3) * 8) + e] = f2bf(v);
    }

    int lrow = lane >> 2;
    int gch = ((lane & 3) - (lane >> 3)) & 3;
    int m16 = lane & 15, q = lane >> 4;
    int wr = (w >> 1) * 64, wcc = (w & 1) * 64;

    for (int nb = 0; nb < 13; nb++) {
        __syncthreads();
        #pragma unroll
        for (int kc = 0; kc < 3; kc++) {
            const unsigned short* gb = Wc + ((size_t)(nb * 128 + 32 * w + lrow)) * KP1
                                          + kc * 32 + gch * 8;
            unsigned short* lb = Bs + kc * 4096 + (32 * w) * 32;
            async_ld16(gb, lb);
            async_ld16(gb + 16 * KP1, lb + 16 * 32);
        }
        __syncthreads();

        f32x4_t acc[4][4];
        #pragma unroll
        for (int i = 0; i < 4; i++)
            #pragma unroll
            for (int j = 0; j < 4; j++)
                acc[i][j] = (f32x4_t)(0.f);

        #pragma unroll
        for (int kc = 0; kc < 3; kc++) {
            bf16x8_t af[4], bf[4];
            #pragma unroll
            for (int i = 0; i < 4; i++) {
                int row = wr + i * 16 + m16;
                af[i] = *(const bf16x8_t*)&As[kc * 4096 + row * 32 + (((q + (row >> 1)) & 3) * 8)];
            }
            #pragma unroll
            for (int j = 0; j < 4; j++) {
                int row = wcc + j * 16 + m16;
                bf[j] = *(const bf16x8_t*)&Bs[kc * 4096 + row * 32 + (((q + (row >> 1)) & 3) * 8)];
            }
            #pragma unroll
            for (int i = 0; i < 4; i++)
                #pragma unroll
                for (int j = 0; j < 4; j++)
                    acc[i][j] = __builtin_amdgcn_mfma_f32_16x16x32_bf16(af[i], bf[j], acc[i][j], 0, 0, 0);
        }

        #pragma unroll
        for (int j = 0; j < 4; j++) {
            int ng = nb * 128 + wcc + j * 16 + m16;
            if (ng >= 2 * HCDIM) continue;
            unsigned short* dst = (ng < HCDIM) ? (xl + ng) : (xr + (ng - HCDIM));
            #pragma unroll
            for (int i = 0; i < 4; i++) {
                #pragma unroll
                for (int rr = 0; rr < 4; rr++) {
                    int row = bm + wr + i * 16 + q * 4 + rr;
                    if (row < M) dst[(size_t)row * HCDIM] = f2bf(acc[i][j][rr]);
                }
            }
        }
    }
}

// ---------------------------------------------------------------------------
// GATv2 aggregation v6 (stable: 8-lane groups, 5 waves per 4 nodes).
// ---------------------------------------------------------------------------
__device__ __forceinline__ void gat_body8(
        const char* __restrict__ xlb, unsigned bo, bool lo7, bool live,
        v2f r0, v2f r1, v2f r2, v2f r3, v2f r4,
        v2f a0, v2f a1, v2f a2, v2f a3, v2f a4,
        float& l, v2f& c0, v2f& c1, v2f& c2, v2f& c3, v2f& c4) {
    const unsigned int* p = (const unsigned int*)(xlb + bo);
    unsigned int u0 = p[0];
    unsigned int u1 = p[8];
    unsigned int u2 = p[16];
    unsigned int u3 = p[24];
    unsigned int u4 = lo7 ? p[32] : 0u;
    v2f v0 = cvt2(u0), v1 = cvt2(u1), v2v = cvt2(u2), v3 = cvt2(u3), v4 = cvt2(u4);
    v2f t0 = v0 + r0, t1 = v1 + r1, t2 = v2v + r2, t3 = v3 + r3, t4 = v4 + r4;
    v2f m0 = vmax2(t0, t0 * 0.2f);
    v2f m1 = vmax2(t1, t1 * 0.2f);
    v2f m2 = vmax2(t2, t2 * 0.2f);
    v2f m3 = vmax2(t3, t3 * 0.2f);
    v2f m4 = vmax2(t4, t4 * 0.2f);
    v2f s2 = m0 * a0;
    s2 += m1 * a1;
    s2 += m2 * a2;
    s2 += m3 * a3;
    s2 += m4 * a4;
    float part = dpp_red8(s2.x + s2.y);
    float pp = __builtin_amdgcn_exp2f(part);
    pp = live ? pp : 0.f;
    l += pp;
    c0 += pp * v0; c1 += pp * v1; c2 += pp * v2v; c3 += pp * v3; c4 += pp * v4;
}

__global__ __launch_bounds__(256) void gat_kernel(
        const unsigned short* __restrict__ xl, const unsigned short* xr,
        const int* __restrict__ row_ptr, const int* __restrict__ col,
        const float* __restrict__ att, const float* __restrict__ bias1,
        unsigned short* h_out) {
    int wid = blockIdx.x * 4 + (threadIdx.x >> 6);
    int quad = wid / 5;
    int wavein = wid - 5 * quad;
    int lane = threadIdx.x & 63;
    int g = lane >> 3, gl = lane & 7;
    int tau = 8 * wavein + g;            // 0..39 task within quad
    int nl = tau / 10;                   // 0..3
    int head = tau - 10 * nl;            // 0..9
    int node = 4 * quad + nl;
    bool lo7 = gl < 7;

    const float L2E = 1.4426950408889634f;
    const float2* ap = (const float2*)(att + head * CDIM);
    float2 A0 = ap[gl], A1 = ap[gl + 8], A2 = ap[gl + 16], A3 = ap[gl + 24];
    float2 A4 = lo7 ? ap[gl + 32] : make_float2(0.f, 0.f);
    v2f a0, a1, a2, a3, a4;
    a0.x = A0.x * L2E; a0.y = A0.y * L2E;
    a1.x = A1.x * L2E; a1.y = A1.y * L2E;
    a2.x = A2.x * L2E; a2.y = A2.y * L2E;
    a3.x = A3.x * L2E; a3.y = A3.y * L2E;
    a4.x = A4.x * L2E; a4.y = A4.y * L2E;

    unsigned doffb = (unsigned)(head * (CDIM * 2) + gl * 4);    // byte off in row
    const char* xlb = (const char*)xl;
    const unsigned int* rp = (const unsigned int*)((const char*)xr
                              + (unsigned)node * (unsigned)(HCDIM * 2) + doffb);
    v2f r0 = cvt2(rp[0]);
    v2f r1 = cvt2(rp[8]);
    v2f r2 = cvt2(rp[16]);
    v2f r3 = cvt2(rp[24]);
    v2f r4 = lo7 ? cvt2(rp[32]) : (v2f)(0.f);

    int e0 = row_ptr[node], e1 = row_ptr[node + 1];
    int deg = e1 - e0;                                  // >= 1 (self-loop)
    int dF = __builtin_amdgcn_readlane(deg, 0);
    int dL = __builtin_amdgcn_readlane(deg, 63);
    int iters = dF > dL ? dF : dL;

    float l = 0.f;
    v2f c0 = (v2f)(0.f), c1 = (v2f)(0.f), c2 = (v2f)(0.f), c3 = (v2f)(0.f), c4 = (v2f)(0.f);

    const char* colb = (const char*)col;
    unsigned cbase = (unsigned)e0 * 4u;
    unsigned cmax = (unsigned)(deg - 1) * 4u;
    for (int i = 0; i < iters; i += 2) {
        unsigned io = (unsigned)i * 4u;
        unsigned q1 = io < cmax ? io : cmax;
        unsigned io2 = io + 4u;
        unsigned q2 = io2 < cmax ? io2 : cmax;
        int j1 = *(const int*)(colb + (cbase + q1));    // clamped: in-bounds
        int j2 = *(const int*)(colb + (cbase + q2));
        bool lv1 = i < deg;
        bool lv2 = (i + 1) < deg;
        gat_body8(xlb, (unsigned)j1 * (unsigned)(HCDIM * 2) + doffb, lo7, lv1,
                  r0, r1, r2, r3, r4, a0, a1, a2, a3, a4, l, c0, c1, c2, c3, c4);
        gat_body8(xlb, (unsigned)j2 * (unsigned)(HCDIM * 2) + doffb, lo7, lv2,
                  r0, r1, r2, r3, r4, a0, a1, a2, a3, a4, l, c0, c1, c2, c3, c4);
    }

    float inv = 1.f / l;                 // l > 0 (self-loop)
    const float2* bp = (const float2*)(bias1 + head * CDIM);
    unsigned int* op = (unsigned int*)((char*)h_out
                        + (unsigned)node * (unsigned)(HCDIM * 2) + doffb);
    #pragma unroll
    for (int k = 0; k < 5; k++) {
        if (k == 4 && !lo7) break;
        v2f c = (k == 0) ? c0 : (k == 1) ? c1 : (k == 2) ? c2 : (k == 3) ? c3 : c4;
        float2 bb = bp[gl + 8 * k];
        float x0 = c.x * inv + bb.x;
        float x1 = c.y * inv + bb.y;
        x0 = x0 > 0.f ? x0 : (__expf(x0) - 1.f);   // ELU
        x1 = x1 > 0.f ? x1 : (__expf(x1) - 1.f);
        op[8 * k] = (unsigned int)f2bf(x0) | ((unsigned int)f2bf(x1) << 16);
    }
}

// ---------------------------------------------------------------------------
// GCN aggregation v4: 2-deep software pipeline (unchanged from R8, -15 µs).
// ---------------------------------------------------------------------------
__device__ __forceinline__ void gcn_consume(
        float s, bf16x8_t u, ushort4 v4, ushort4 w4,
        float* __restrict__ accA, float* __restrict__ accB, float* __restrict__ accC) {
    #pragma unroll
    for (int k = 0; k < 8; k++) accA[k] = fmaf(s, bf2f((unsigned short)u[k]), accA[k]);
    accB[0] = fmaf(s, bf2f(v4.x), accB[0]);
    accB[1] = fmaf(s, bf2f(v4.y), accB[1]);
    accB[2] = fmaf(s, bf2f(v4.z), accB[2]);
    accB[3] = fmaf(s, bf2f(v4.w), accB[3]);
    accC[0] = fmaf(s, bf2f(w4.x), accC[0]);
    accC[1] = fmaf(s, bf2f(w4.y), accC[1]);
    accC[2] = fmaf(s, bf2f(w4.z), accC[2]);
    accC[3] = fmaf(s, bf2f(w4.w), accC[3]);
}

__global__ __launch_bounds__(256) void gcn_agg_kernel(
        const unsigned short* __restrict__ h, const int* __restrict__ row_ptr,
        const int* __restrict__ col, const float* __restrict__ dinv,
        unsigned short* __restrict__ agg) {
    int node = blockIdx.x * 4 + (threadIdx.x >> 6);
    if (node >= NNODES) return;
    int ln = threadIdx.x & 63;
    bool hasC = ln < 3;
    float accA[8] = {}, accB[4] = {}, accC[4] = {};
    int e0 = row_ptr[node], e1 = row_ptr[node + 1];   // deg >= 1 (self-loop)

    // state 0 <- edge e0
    int j0 = __builtin_amdgcn_readfirstlane(col[e0]);
    const unsigned short* hr0 = h + (size_t)j0 * HCDIM;
    bf16x8_t u0 = *(const bf16x8_t*)(hr0 + 8 * ln);
    ushort4 v0 = *(const ushort4*)(hr0 + 512 + 4 * ln);
    ushort4 w0 = hasC ? *(const ushort4*)(hr0 + 768 + 4 * ln) : make_ushort4(0, 0, 0, 0);
    float s0 = dinv[j0];

    int e = e0;
    for (;;) {
        bool m1 = (e + 1 < e1);
        bf16x8_t u1; ushort4 v1, w1; float s1;
        if (m1) {   // prefetch edge e+1 into state 1 before consuming state 0
            int j1 = __builtin_amdgcn_readfirstlane(col[e + 1]);
            const unsigned short* hr1 = h + (size_t)j1 * HCDIM;
            u1 = *(const bf16x8_t*)(hr1 + 8 * ln);
            v1 = *(const ushort4*)(hr1 + 512 + 4 * ln);
            w1 = hasC ? *(const ushort4*)(hr1 + 768 + 4 * ln) : make_ushort4(0, 0, 0, 0);
            s1 = dinv[j1];
        }
        gcn_consume(s0, u0, v0, w0, accA, accB, accC);
        if (!m1) break;
        e++;
        bool m2 = (e + 1 < e1);
        if (m2) {   // prefetch edge e+1 into state 0 before consuming state 1
            int j2 = __builtin_amdgcn_readfirstlane(col[e + 1]);
            const unsigned short* hr2 = h + (size_t)j2 * HCDIM;
            u0 = *(const bf16x8_t*)(hr2 + 8 * ln);
            v0 = *(const ushort4*)(hr2 + 512 + 4 * ln);
            w0 = hasC ? *(const ushort4*)(hr2 + 768 + 4 * ln) : make_ushort4(0, 0, 0, 0);
            s0 = dinv[j2];
        }
        gcn_consume(s1, u1, v1, w1, accA, accB, accC);
        if (!m2) break;
        e++;
    }

    float di = dinv[node];
    unsigned short* ar = agg + (size_t)node * HCDIM;
    ushort4 o1, o2, ob;
    o1.x = f2bf(accA[0] * di); o1.y = f2bf(accA[1] * di);
    o1.z = f2bf(accA[2] * di); o1.w = f2bf(accA[3] * di);
    o2.x = f2bf(accA[4] * di); o2.y = f2bf(accA[5] * di);
    o2.z = f2bf(accA[6] * di); o2.w = f2bf(accA[7] * di);
    ob.x = f2bf(accB[0] * di); ob.y = f2bf(accB[1] * di);
    ob.z = f2bf(accB[2] * di); ob.w = f2bf(accB[3] * di);
    *(ushort4*)(ar + 8 * ln) = o1;
    *(ushort4*)(ar + 8 * ln + 4) = o2;
    *(ushort4*)(ar + 512 + 4 * ln) = ob;
    if (hasC) {
        ushort4 oc;
        oc.x = f2bf(accC[0] * di); oc.y = f2bf(accC[1] * di);
        oc.z = f2bf(accC[2] * di); oc.w = f2bf(accC[3] * di);
        *(ushort4*)(ar + 768 + 4 * ln) = oc;
    }
}

// ---------------------------------------------------------------------------
// BT prep: BT[n][k] = bf16(W_gcn[k][n]), zero-padded to [NPAD][KPAD=800]
// ---------------------------------------------------------------------------
__global__ void btprep_kernel(const float* __restrict__ W, unsigned short* __restrict__ BT) {
    int idx = blockIdx.x * 256 + threadIdx.x;
    if (idx >= NPAD * KPAD) return;
    int n = idx / KPAD, k = idx - n * KPAD;
    float v = (n < HCDIM && k < HCDIM) ? W[(size_t)k * HCDIM + n] : 0.f;
    BT[idx] = f2bf(v);
}

// ---------------------------------------------------------------------------
// GEMM2 MFMA fused v11: BK=32 dbuf (4 blocks/CU), KPAD=800 (25 tiles, was
// 26 — dead K-tile removed). NOTE on bank conflicts (R12/R14 bit-identical
// 9.1M): with 64-B rows, strided lane-phase grouping confines each phase to
// one row parity -> 4 bank-groups for 8 lanes = 2-way minimum; no 4-slot
// rotation can fix it (structural to gload_lds-linear 64B rows). Costs ~8 µs,
// paid for by +10% occupancy vs BK=64. Degree-2 rotation kept (harmless).
// ---------------------------------------------------------------------------
__global__ __launch_bounds__(256) void gemm2_pool_kernel(
        const unsigned short* __restrict__ A, const unsigned short* __restrict__ BT,
        const float* __restrict__ bias, const int* __restrict__ batch,
        float* __restrict__ out, int M) {
    int f = blockIdx.x;
    int xcd = f & 7, inner = f >> 3;
    int bq = inner / 7, colt = inner - 7 * bq;
    int band = 8 * bq + xcd;
    if (band >= (M + BM - 1) / BM) return;   // block-uniform
    int bm = band * BM, bn = colt * BN;

    __shared__ unsigned short smem[2 * BUFO];       // 32 KB: {buf}{As|Bs}[128][32]
    __shared__ int bsh[BM];

    int t = threadIdx.x;
    int lane = t & 63, w = t >> 6;

    if (t < BM) {
        int row = bm + t;
        bsh[t] = (row < M) ? batch[row] : -1;
    }

    int m16 = lane & 15, q = lane >> 4;
    int wr = (w >> 1) * 64, wc = (w & 1) * 64;

    // live 16-col groups for this wave (wave-uniform): 4 for full tiles,
    // 1 for tail tile wc=0 (cols 768..783 -> 12 real), 0 for tail wc=64.
    int remc = HCDIM - bn - wc;
    int nj = (remc >= 64) ? 4 : (remc > 0 ? ((remc + 15) >> 4) : 0);

    int lrow4 = lane >> 2;              // 16 rows per load instruction
    int c4 = lane & 3;
    int gch = (c4 - lrow4 - (lrow4 >> 2)) & 3;   // degree-2 pre-swizzled chunk
    const unsigned short* gA = A  + (size_t)(bm + 32 * w + lrow4) * HCDIM + gch * 8;
    const unsigned short* gB = BT + (size_t)(bn + 32 * w + lrow4) * KPAD  + gch * 8;
    unsigned short* lA = smem + (32 * w) * 32;              // + buf*BUFO
    unsigned short* lB = smem + 128 * 32 + (32 * w) * 32;   // + buf*BUFO

    f32x4_t acc[4][4];
    #pragma unroll
    for (int i = 0; i < 4; i++)
        #pragma unroll
        for (int j = 0; j < 4; j++)
            acc[i][j] = (f32x4_t)(0.f);

    // prologue: stage tile 0 into buf 0 (4 loads/thread); counted wait in loop
    #pragma unroll
    for (int ib = 0; ib < 2; ib++) {
        async_ld16(gA + (size_t)(16 * ib) * HCDIM, lA + (16 * ib) * 32);
        async_ld16(gB + (size_t)(16 * ib) * KPAD,  lB + (16 * ib) * 32);
    }

    for (int tt = 0; tt < NKT; tt++) {
        int cur = tt & 1;
        // issue next tile's loads; they STAY IN FLIGHT across the barrier
        if (tt + 1 < NKT) {
            int k0 = (tt + 1) * BK;
            unsigned short* dA = lA + (cur ? 0 : BUFO);
            unsigned short* dB = lB + (cur ? 0 : BUFO);
            #pragma unroll
            for (int ib = 0; ib < 2; ib++) {
                async_ld16(gA + (size_t)(16 * ib) * HCDIM + k0, dA + (16 * ib) * 32);
                async_ld16(gB + (size_t)(16 * ib) * KPAD  + k0, dB + (16 * ib) * 32);
            }
            asm volatile("s_waitcnt vmcnt(4)" ::: "memory");   // tile tt landed
        } else {
            asm volatile("s_waitcnt vmcnt(0)" ::: "memory");   // last tile
        }
        __builtin_amdgcn_s_barrier();   // publish all waves' tile-tt LDS writes

        const unsigned short* As = smem + (cur ? BUFO : 0);
        const unsigned short* Bs = As + 128 * 32;

        if (nj > 0) {
            bf16x8_t af[4], bf[4];
            #pragma unroll
            for (int i = 0; i < 4; i++) {
                int row = wr + i * 16 + m16;
                af[i] = *(const bf16x8_t*)&As[row * 32 + ((q + row + (row >> 2)) & 3) * 8];
            }
            #pragma unroll
            for (int j = 0; j < 4; j++) {
                if (j >= nj) break;
                int row = wc + j * 16 + m16;
                bf[j] = *(const bf16x8_t*)&Bs[row * 32 + ((q + row + (row >> 2)) & 3) * 8];
            }
            #pragma unroll
            for (int j = 0; j < 4; j++) {
                if (j >= nj) break;
                #pragma unroll
                for (int i = 0; i < 4; i++)
                    acc[i][j] = __builtin_amdgcn_mfma_f32_16x16x32_bf16(af[i], bf[j], acc[i][j], 0, 0, 0);
            }
        }

        // all waves done reading buf[cur] before iter tt+1 overwrites it
        __builtin_amdgcn_s_barrier();
    }

    float bvj[4];
    #pragma unroll
    for (int j = 0; j < 4; j++) {
        int gcc = bn + wc + j * 16 + m16;
        bvj[j] = (gcc < HCDIM) ? bias[gcc] : 0.f;
    }

    #pragma unroll
    for (int p = 0; p < 2; p++) {
        __syncthreads();
        if ((w >> 1) == p) {
            #pragma unroll
            for (int i = 0; i < 4; i++) {
                #pragma unroll
                for (int j = 0; j < 4; j++) {
                    int colc = wc + j * 16 + m16;
                    ushort4 o;
                    float v0 = acc[i][j][0] + bvj[j];
                    float v1 = acc[i][j][1] + bvj[j];
                    float v2 = acc[i][j][2] + bvj[j];
                    float v3 = acc[i][j][3] + bvj[j];
                    o.x = f2bf(v0 > 0.f ? v0 : 0.f);
                    o.y = f2bf(v1 > 0.f ? v1 : 0.f);
                    o.z = f2bf(v2 > 0.f ? v2 : 0.f);
                    o.w = f2bf(v3 > 0.f ? v3 : 0.f);
                    *(ushort4*)&smem[colc * LDT + i * 16 + q * 4] = o;
                }
            }
        }
        __syncthreads();
        int colp = t & 127;
        int rb = (t >> 7) * 32;
        int gc = bn + colp;
        if (gc < HCDIM) {
            int cur = -1; float mx = 0.f, sm = 0.f;
            bool done = false;
            for (int rr = rb; rr < rb + 32 && !done; rr += 4) {
                ushort4 u = *(const ushort4*)&smem[colp * LDT + rr];
                unsigned short us[4] = {u.x, u.y, u.z, u.w};
                #pragma unroll
                for (int s2 = 0; s2 < 4; s2++) {
                    int b = bsh[64 * p + rr + s2];
                    if (b < 0) { done = true; break; }
                    float v = bf2f(us[s2]);
                    if (b != cur) {
                        if (cur >= 0) {
                            atomicMax((int*)(out + (size_t)cur * (2 * HCDIM) + gc), __float_as_int(mx));
                            atomicAdd(out + (size_t)cur * (2 * HCDIM) + HCDIM + gc, sm);
                        }
                        cur = b; mx = v; sm = v;
                    } else { mx = fmaxf(mx, v); sm += v; }
                }
            }
            if (cur >= 0) {
                atomicMax((int*)(out + (size_t)cur * (2 * HCDIM) + gc), __float_as_int(mx));
                atomicAdd(out + (size_t)cur * (2 * HCDIM) + HCDIM + gc, sm);
            }
        }
    }
}

// divide the mean slots by counts
__global__ void finalize_kernel(float* __restrict__ out, const int* __restrict__ bst) {
    int i = blockIdx.x * blockDim.x + threadIdx.x;
    if (i >= NBATCH * HCDIM) return;
    int b = i / HCDIM, c = i - b * HCDIM;
    int cnt = bst[b + 1] - bst[b];
    out[(size_t)b * (2 * HCDIM) + HCDIM + c] /= (float)(cnt > 0 ? cnt : 1);
}

// ---------------------------------------------------------------------------
extern "C" void kernel_launch(void* const* d_in, const int* in_sizes, int n_in,
                              void* d_out, int out_size, void* d_ws, size_t ws_size,
                              hipStream_t stream) {
    const float* x       = (const float*)d_in[0];
    const int*   ei      = (const int*)d_in[1];
    const int*   batch   = (const int*)d_in[2];
    const float* W_l     = (const float*)d_in[3];
    const float* W_r     = (const float*)d_in[4];
    const float* att     = (const float*)d_in[5];
    const float* bias1   = (const float*)d_in[6];
    const float* W_gcn   = (const float*)d_in[7];
    const float* bias_gcn= (const float*)d_in[8];
    float* out = (float*)d_out;

    char* w = (char*)d_ws;
    const size_t BIGH = (size_t)NNODES * HCDIM * sizeof(unsigned short);  // 78,000,000
    unsigned short* xl  = (unsigned short*)(w);          // later reused as agg
    unsigned short* xr  = (unsigned short*)(w + BIGH);   // becomes h; later BT
    unsigned short* agg = xl;
    unsigned short* BT  = xr;                            // h dead after gcn_agg
    char* sm = w + 2 * BIGH;
    int*   rowp = (int*)(sm);                    sm += 50048 * 4;
    int*   col  = (int*)(sm);                    sm += 450048 * 4;
    float* dinv = (float*)(sm);                  sm += 50048 * 4;
    int*   bst  = (int*)(sm);                    sm += 512 * 4;
    int*   bsum = (int*)(sm);                    sm += 256 * 4;
    char* S = sm;                                sm += 426240;
    int*   deg  = (int*)(S);
    int*   curs = (int*)(S + 200192);
    unsigned short* Wc = (unsigned short*)(S);   // NP1*KP1*2 = 319,488 B < 426,240
    size_t needed = (size_t)(sm - (char*)d_ws);
    if (ws_size < needed) return;   // fail soft instead of OOB fault

    // --- zero-init (out for atomics + deg) ---
    zero_kernel<<<(NBATCH * 2 * HCDIM + 255) / 256, 256, 0, stream>>>(
        out, NBATCH * 2 * HCDIM, deg, NNODES);

    // --- CSR build ---
    {
        int eblocks = (ETOT + 255) / 256;
        int nblocks = (NNODES + 255) / 256;     // 196
        count_kernel<<<eblocks, 256, 0, stream>>>(ei, deg);
        scan1_kernel<<<nblocks, 256, 0, stream>>>(deg, rowp, bsum);
        scan2_kernel<<<1, 512, 0, stream>>>(bsum, rowp, nblocks, batch, bst);
        scan3_kernel<<<nblocks, 256, 0, stream>>>(rowp, bsum, curs, deg, dinv);
        fill_kernel<<<eblocks, 256, 0, stream>>>(ei, curs, col);
    }

    // --- Wc = [W_l|W_r]^T bf16 padded to K=96 (overwrites deg/curs) ---
    wprep_kernel<<<(NP1 * KP1 + 255) / 256, 256, 0, stream>>>(W_l, W_r, Wc);

    // --- fused GEMM1 (MFMA, K=96): xl|xr = x @ [W_l|W_r] ---
    gemm1_kernel<<<(NNODES + 127) / 128, 256, 0, stream>>>(x, Wc, xl, xr, NNODES);

    // --- GATv2 + ELU (writes h over xr); v6: 5 waves per 4 nodes ---
    {
        int waves = (NNODES / 4) * 5;          // 62500
        int blocks = waves / 4;                // 15625 (exact)
        gat_kernel<<<blocks, 256, 0, stream>>>(xl, xr, rowp, col, att, bias1, xr);
    }

    // --- GCN aggregate (h -> agg, overwrites xl space; 2-deep pipelined) ---
    gcn_agg_kernel<<<(NNODES + 3) / 4, 256, 0, stream>>>(xr, rowp, col, dinv, agg);

    // --- W_gcn^T -> bf16 padded to K=800 (into xr region; h is dead) ---
    btprep_kernel<<<(NPAD * KPAD + 255) / 256, 256, 0, stream>>>(W_gcn, BT);

    // --- GEMM2 (MFMA, BK=32 dbuf, KPAD=800, 4 blocks/CU) + pooling ---
    {
        int nb = (NNODES + BM - 1) / BM;       // 391
        int gx = 8 * ((nb + 7) / 8) * 7;       // 2744
        gemm2_pool_kernel<<<gx, 256, 0, stream>>>(agg, BT, bias_gcn, batch, out, NNODES);
    }

    // --- finalize means ---
    finalize_kernel<<<(NBATCH * HCDIM + 255) / 256, 256, 0, stream>>>(out, bst);
}